// Round 8
// baseline (182.975 us; speedup 1.0000x reference)
//
#include <hip/hip_runtime.h>
#include <float.h>

#define NL 32
#define NT 16384
#define NE 64
#define NK 8
#define NBLK 2048
#define LOG2E 1.4426950408889634f

typedef float floatx4 __attribute__((ext_vector_type(4)));

// DPP control codes
#define DPP_QUAD_XOR1 0xB1   // quad_perm [1,0,3,2]
#define DPP_QUAD_XOR2 0x4E   // quad_perm [2,3,0,1]
#define DPP_ROW_ROR4  0x124  // row_ror:4
#define DPP_ROW_ROR8  0x128  // row_ror:8

template <int CTRL>
__device__ __forceinline__ float dppmv(float v) {
    return __int_as_float(
        __builtin_amdgcn_update_dpp(0, __float_as_int(v), CTRL, 0xF, 0xF, true));
}

// reduce across a 16-lane group (DPP row = 16 lanes on CDNA)
__device__ __forceinline__ float grp_max(float v) {
    v = fmaxf(v, dppmv<DPP_QUAD_XOR1>(v));
    v = fmaxf(v, dppmv<DPP_QUAD_XOR2>(v));
    v = fmaxf(v, dppmv<DPP_ROW_ROR4>(v));
    v = fmaxf(v, dppmv<DPP_ROW_ROR8>(v));
    return v;
}
__device__ __forceinline__ float grp_sum(float v) {
    v = v + dppmv<DPP_QUAD_XOR1>(v);
    v = v + dppmv<DPP_QUAD_XOR2>(v);
    v = v + dppmv<DPP_ROW_ROR4>(v);
    v = v + dppmv<DPP_ROW_ROR8>(v);
    return v;
}

// descending compare-exchange
__device__ __forceinline__ void ce(float& a, float& b) {
    float hi = fmaxf(a, b);
    float lo = fminf(a, b);
    a = hi; b = lo;
}

__global__ __launch_bounds__(256, 8) void bl_fused(const float* __restrict__ logits,
                                                   float* __restrict__ g_w,
                                                   float* __restrict__ g_c,
                                                   unsigned int* __restrict__ cnt,
                                                   float* __restrict__ out) {
    const int tid  = threadIdx.x;
    const int lane = tid & 63;
    const int wv   = tid >> 6;
    const long slab = ((long)blockIdx.x * 4 + wv) * 64;  // first token of this wave
    const int layer = (int)(slab >> 14);                 // 16384 tokens per layer

    // chunk j: 1KB coalesced; lane i holds experts (i&15)*4..+3 of token slab+4j+(i>>4)
    const floatx4* p = (const floatx4*)(logits + slab * NE);

    float wacc[4] = {0.f, 0.f, 0.f, 0.f};
    float cacc[4] = {0.f, 0.f, 0.f, 0.f};

    // depth-6 rolling prefetch ring (nt: read-once stream, don't allocate)
    floatx4 buf[6];
#pragma unroll
    for (int j = 0; j < 6; ++j) buf[j] = __builtin_nontemporal_load(&p[j * 64 + lane]);

#pragma unroll
    for (int j = 0; j < 16; ++j) {
        const floatx4 cur = buf[j % 6];
        if (j + 6 < 16) buf[j % 6] = __builtin_nontemporal_load(&p[(j + 6) * 64 + lane]);

        // exp-space immediately (monotone -> same top-k selection)
        const float x0 = __builtin_amdgcn_exp2f(cur.x * LOG2E);
        const float x1 = __builtin_amdgcn_exp2f(cur.y * LOG2E);
        const float x2 = __builtin_amdgcn_exp2f(cur.z * LOG2E);
        const float x3 = __builtin_amdgcn_exp2f(cur.w * LOG2E);

        const float den = grp_sum((x0 + x1) + (x2 + x3));
        const float inv = __builtin_amdgcn_rcpf(den);

        // lane-local sorted queue (desc) of its 4 exp-values
        float q0 = x0, q1 = x1, q2 = x2, q3 = x3;
        ce(q0, q1); ce(q2, q3); ce(q0, q2); ce(q1, q3); ce(q1, q2);

        // 8 pop rounds across the 16-lane group -> threshold = 8th largest of 64
        float thr = 0.f;
#pragma unroll
        for (int k = 0; k < NK; ++k) {
            const float m = grp_max(q0);
            thr = m;
            if (k < NK - 1) {
                const bool hit = (q0 == m);
                q0 = hit ? q1 : q0;
                q1 = hit ? q2 : q1;
                q2 = hit ? q3 : q2;
                q3 = hit ? -1.0f : q3;   // x >= 0 always, -1 is a safe sentinel
            }
        }

        // top-k membership counts (lane-local experts), in exp-space
        cacc[0] += (x0 >= thr) ? 1.f : 0.f;
        cacc[1] += (x1 >= thr) ? 1.f : 0.f;
        cacc[2] += (x2 >= thr) ? 1.f : 0.f;
        cacc[3] += (x3 >= thr) ? 1.f : 0.f;

        // softmax weight accumulation
        wacc[0] = fmaf(x0, inv, wacc[0]);
        wacc[1] = fmaf(x1, inv, wacc[1]);
        wacc[2] = fmaf(x2, inv, wacc[2]);
        wacc[3] = fmaf(x3, inv, wacc[3]);
    }

    // combine the 4 groups of the wave (lanes with equal (lane&15) share experts)
#pragma unroll
    for (int r = 0; r < 4; ++r) {
        wacc[r] += __shfl_xor(wacc[r], 16);
        wacc[r] += __shfl_xor(wacc[r], 32);
        cacc[r] += __shfl_xor(cacc[r], 16);
        cacc[r] += __shfl_xor(cacc[r], 32);
    }

    // block-level combine in LDS, then one batch of device-scope atomics
    __shared__ float comb[2][NE][4];
    __shared__ int last_flag;
    if (lane < 16) {
#pragma unroll
        for (int r = 0; r < 4; ++r) {
            comb[0][lane * 4 + r][wv] = wacc[r];
            comb[1][lane * 4 + r][wv] = cacc[r];
        }
    }
    __syncthreads();
    if (tid < 128) {
        const int s = tid >> 6, e = tid & 63;
        const float val = comb[s][e][0] + comb[s][e][1] + comb[s][e][2] + comb[s][e][3];
        float* dst = s ? g_c : g_w;
        atomicAdd(&dst[layer * NE + e], val);
    }
    __syncthreads();   // all atomics of this block issued before the flag bump

    if (tid == 0) {
        __threadfence();  // make this block's adds visible at device scope
        const unsigned int old =
            __hip_atomic_fetch_add(cnt, 1u, __ATOMIC_ACQ_REL, __HIP_MEMORY_SCOPE_AGENT);
        last_flag = (old == NBLK - 1) ? 1 : 0;
    }
    __syncthreads();

    if (last_flag) {
        // final reduce: 2048 products, coherent atomic-loads (cross-XCD safe)
        float acc = 0.f;
#pragma unroll
        for (int k = 0; k < 8; ++k) {
            const int i = tid + k * 256;
            const float w = __hip_atomic_load(&g_w[i], __ATOMIC_RELAXED,
                                              __HIP_MEMORY_SCOPE_AGENT);
            const float c = __hip_atomic_load(&g_c[i], __ATOMIC_RELAXED,
                                              __HIP_MEMORY_SCOPE_AGENT);
            acc = fmaf(w, c, acc);
        }
        __shared__ float red[256];
        red[tid] = acc;
        __syncthreads();
        for (int s = 128; s > 0; s >>= 1) {
            if (tid < s) red[tid] += red[tid + s];
            __syncthreads();
        }
        if (tid == 0) {
            // loss = 0.01 * sum_l[ (E/(T*K)) * sum_e counts * (wsum/T) ]
            const float factor = (float)(0.01 * ((double)NE / ((double)NT * NK)) / (double)NT);
            out[0] = red[0] * factor;
        }
    }
}

extern "C" void kernel_launch(void* const* d_in, const int* in_sizes, int n_in,
                              void* d_out, int out_size, void* d_ws, size_t ws_size,
                              hipStream_t stream) {
    const float* logits = (const float*)d_in[0];
    float* g_w = (float*)d_ws;                    // [NL*NE] = 8 KB
    float* g_c = g_w + NL * NE;                   // [NL*NE] = 8 KB
    unsigned int* cnt = (unsigned int*)(g_c + NL * NE);

    // zero accumulators + completion counter (deterministic per launch, graph-safe)
    (void)hipMemsetAsync(d_ws, 0, 2 * NL * NE * sizeof(float) + sizeof(unsigned int), stream);
    bl_fused<<<dim3(NBLK), dim3(256), 0, stream>>>(logits, g_w, g_c, cnt, (float*)d_out);
}

// Round 9
// 136.849 us; speedup vs baseline: 1.3371x; 1.3371x over previous
//
#include <hip/hip_runtime.h>
#include <float.h>

#define NL 32
#define NT 16384
#define NE 64
#define NK 8
#define NBLK 2048
#define LOG2E 1.4426950408889634f

// DPP control codes
#define DPP_QUAD_XOR1 0xB1   // quad_perm [1,0,3,2]
#define DPP_QUAD_XOR2 0x4E   // quad_perm [2,3,0,1]
#define DPP_ROW_ROR4  0x124  // row_ror:4
#define DPP_ROW_ROR8  0x128  // row_ror:8

template <int CTRL>
__device__ __forceinline__ float dppmv(float v) {
    return __int_as_float(
        __builtin_amdgcn_update_dpp(0, __float_as_int(v), CTRL, 0xF, 0xF, true));
}

// reduce across a 16-lane group (DPP row = 16 lanes on CDNA)
__device__ __forceinline__ float grp_max(float v) {
    v = fmaxf(v, dppmv<DPP_QUAD_XOR1>(v));
    v = fmaxf(v, dppmv<DPP_QUAD_XOR2>(v));
    v = fmaxf(v, dppmv<DPP_ROW_ROR4>(v));
    v = fmaxf(v, dppmv<DPP_ROW_ROR8>(v));
    return v;
}
__device__ __forceinline__ float grp_sum(float v) {
    v = v + dppmv<DPP_QUAD_XOR1>(v);
    v = v + dppmv<DPP_QUAD_XOR2>(v);
    v = v + dppmv<DPP_ROW_ROR4>(v);
    v = v + dppmv<DPP_ROW_ROR8>(v);
    return v;
}

// descending compare-exchange
__device__ __forceinline__ void ce(float& a, float& b) {
    float hi = fmaxf(a, b);
    float lo = fminf(a, b);
    a = hi; b = lo;
}

__global__ __launch_bounds__(256, 8) void bl_fused(const float* __restrict__ logits,
                                                   float* __restrict__ g_w,
                                                   float* __restrict__ g_c,
                                                   unsigned int* __restrict__ cnt,
                                                   float* __restrict__ out) {
    const int tid  = threadIdx.x;
    const int lane = tid & 63;
    const int wv   = tid >> 6;
    const long slab = ((long)blockIdx.x * 4 + wv) * 64;  // first token of this wave
    const int layer = (int)(slab >> 14);                 // 16384 tokens per layer

    // chunk j: 1KB coalesced; lane i holds experts (i&15)*4..+3 of token slab+4j+(i>>4)
    const float4* p = (const float4*)(logits + slab * NE);

    float wacc[4] = {0.f, 0.f, 0.f, 0.f};
    float cacc[4] = {0.f, 0.f, 0.f, 0.f};

    // depth-4 rolling prefetch ring; all indices static after full unroll
    float4 buf[4];
#pragma unroll
    for (int j = 0; j < 4; ++j) buf[j] = p[j * 64 + lane];

#pragma unroll
    for (int j = 0; j < 16; ++j) {
        const float4 cur = buf[j & 3];
        if (j + 4 < 16) buf[j & 3] = p[(j + 4) * 64 + lane];

        // exp-space immediately (monotone -> same top-k selection)
        const float x0 = __builtin_amdgcn_exp2f(cur.x * LOG2E);
        const float x1 = __builtin_amdgcn_exp2f(cur.y * LOG2E);
        const float x2 = __builtin_amdgcn_exp2f(cur.z * LOG2E);
        const float x3 = __builtin_amdgcn_exp2f(cur.w * LOG2E);

        const float den = grp_sum((x0 + x1) + (x2 + x3));
        const float inv = __builtin_amdgcn_rcpf(den);

        // lane-local sorted queue (desc) of its 4 exp-values
        float q0 = x0, q1 = x1, q2 = x2, q3 = x3;
        ce(q0, q1); ce(q2, q3); ce(q0, q2); ce(q1, q3); ce(q1, q2);

        // 8 pop rounds across the 16-lane group -> threshold = 8th largest of 64
        float thr = 0.f;
#pragma unroll
        for (int k = 0; k < NK; ++k) {
            const float m = grp_max(q0);
            thr = m;
            if (k < NK - 1) {
                const bool hit = (q0 == m);
                q0 = hit ? q1 : q0;
                q1 = hit ? q2 : q1;
                q2 = hit ? q3 : q2;
                q3 = hit ? -1.0f : q3;   // x >= 0 always, -1 is a safe sentinel
            }
        }

        // top-k membership counts (lane-local experts), in exp-space
        cacc[0] += (x0 >= thr) ? 1.f : 0.f;
        cacc[1] += (x1 >= thr) ? 1.f : 0.f;
        cacc[2] += (x2 >= thr) ? 1.f : 0.f;
        cacc[3] += (x3 >= thr) ? 1.f : 0.f;

        // softmax weight accumulation
        wacc[0] = fmaf(x0, inv, wacc[0]);
        wacc[1] = fmaf(x1, inv, wacc[1]);
        wacc[2] = fmaf(x2, inv, wacc[2]);
        wacc[3] = fmaf(x3, inv, wacc[3]);
    }

    // combine the 4 groups of the wave (lanes with equal (lane&15) share experts)
#pragma unroll
    for (int r = 0; r < 4; ++r) {
        wacc[r] += __shfl_xor(wacc[r], 16);
        wacc[r] += __shfl_xor(wacc[r], 32);
        cacc[r] += __shfl_xor(cacc[r], 16);
        cacc[r] += __shfl_xor(cacc[r], 32);
    }

    // block-level combine in LDS, then one batch of device-scope atomics
    __shared__ float comb[2][NE][4];
    __shared__ int last_flag;
    if (lane < 16) {
#pragma unroll
        for (int r = 0; r < 4; ++r) {
            comb[0][lane * 4 + r][wv] = wacc[r];
            comb[1][lane * 4 + r][wv] = cacc[r];
        }
    }
    __syncthreads();
    if (tid < 128) {
        const int s = tid >> 6, e = tid & 63;
        const float val = comb[s][e][0] + comb[s][e][1] + comb[s][e][2] + comb[s][e][3];
        float* dst = s ? g_c : g_w;
        atomicAdd(&dst[layer * NE + e], val);
    }
    __syncthreads();   // all atomics of this block issued before the flag bump

    if (tid == 0) {
        __threadfence();  // make this block's adds visible at device scope
        const unsigned int old =
            __hip_atomic_fetch_add(cnt, 1u, __ATOMIC_ACQ_REL, __HIP_MEMORY_SCOPE_AGENT);
        last_flag = (old == NBLK - 1) ? 1 : 0;
    }
    __syncthreads();

    if (last_flag) {
        // final reduce: 2048 products, coherent atomic-loads (cross-XCD safe)
        float acc = 0.f;
#pragma unroll
        for (int k = 0; k < 8; ++k) {
            const int i = tid + k * 256;
            const float w = __hip_atomic_load(&g_w[i], __ATOMIC_RELAXED,
                                              __HIP_MEMORY_SCOPE_AGENT);
            const float c = __hip_atomic_load(&g_c[i], __ATOMIC_RELAXED,
                                              __HIP_MEMORY_SCOPE_AGENT);
            acc = fmaf(w, c, acc);
        }
        __shared__ float red[256];
        red[tid] = acc;
        __syncthreads();
        for (int s = 128; s > 0; s >>= 1) {
            if (tid < s) red[tid] += red[tid + s];
            __syncthreads();
        }
        if (tid == 0) {
            // loss = 0.01 * sum_l[ (E/(T*K)) * sum_e counts * (wsum/T) ]
            const float factor = (float)(0.01 * ((double)NE / ((double)NT * NK)) / (double)NT);
            out[0] = red[0] * factor;
        }
    }
}

extern "C" void kernel_launch(void* const* d_in, const int* in_sizes, int n_in,
                              void* d_out, int out_size, void* d_ws, size_t ws_size,
                              hipStream_t stream) {
    const float* logits = (const float*)d_in[0];
    float* g_w = (float*)d_ws;                    // [NL*NE] = 8 KB
    float* g_c = g_w + NL * NE;                   // [NL*NE] = 8 KB
    unsigned int* cnt = (unsigned int*)(g_c + NL * NE);

    // zero accumulators + completion counter (deterministic per launch, graph-safe)
    (void)hipMemsetAsync(d_ws, 0, 2 * NL * NE * sizeof(float) + sizeof(unsigned int), stream);
    bl_fused<<<dim3(NBLK), dim3(256), 0, stream>>>(logits, g_w, g_c, cnt, (float*)d_out);
}

// Round 10
// 92.165 us; speedup vs baseline: 1.9853x; 1.4848x over previous
//
#include <hip/hip_runtime.h>
#include <float.h>

#define NL 32
#define NT 16384
#define NE 64
#define NK 8
#define NBLK 2048
#define LOG2E 1.4426950408889634f

// DPP control codes
#define DPP_QUAD_XOR1 0xB1   // quad_perm [1,0,3,2]
#define DPP_QUAD_XOR2 0x4E   // quad_perm [2,3,0,1]
#define DPP_ROW_ROR4  0x124  // row_ror:4
#define DPP_ROW_ROR8  0x128  // row_ror:8

template <int CTRL>
__device__ __forceinline__ float dppmv(float v) {
    return __int_as_float(
        __builtin_amdgcn_update_dpp(0, __float_as_int(v), CTRL, 0xF, 0xF, true));
}

// reduce across a 16-lane group (DPP row = 16 lanes on CDNA)
__device__ __forceinline__ float grp_max(float v) {
    v = fmaxf(v, dppmv<DPP_QUAD_XOR1>(v));
    v = fmaxf(v, dppmv<DPP_QUAD_XOR2>(v));
    v = fmaxf(v, dppmv<DPP_ROW_ROR4>(v));
    v = fmaxf(v, dppmv<DPP_ROW_ROR8>(v));
    return v;
}
__device__ __forceinline__ float grp_sum(float v) {
    v = v + dppmv<DPP_QUAD_XOR1>(v);
    v = v + dppmv<DPP_QUAD_XOR2>(v);
    v = v + dppmv<DPP_ROW_ROR4>(v);
    v = v + dppmv<DPP_ROW_ROR8>(v);
    return v;
}

// descending compare-exchange
__device__ __forceinline__ void ce(float& a, float& b) {
    float hi = fmaxf(a, b);
    float lo = fminf(a, b);
    a = hi; b = lo;
}

__global__ __launch_bounds__(256, 4) void bl_fused(const float* __restrict__ logits,
                                                   float* __restrict__ g_w,
                                                   float* __restrict__ g_c,
                                                   unsigned int* __restrict__ cnt,
                                                   float* __restrict__ out) {
    const int tid  = threadIdx.x;
    const int lane = tid & 63;
    const int wv   = tid >> 6;
    const long slab = ((long)blockIdx.x * 4 + wv) * 64;  // first token of this wave
    const int layer = (int)(slab >> 14);                 // 16384 tokens per layer

    // chunk j: 1KB coalesced; lane i holds experts (i&15)*4..+3 of token slab+4j+(i>>4)
    const float4* p = (const float4*)(logits + slab * NE);

    float wacc[4] = {0.f, 0.f, 0.f, 0.f};
    float cacc[4] = {0.f, 0.f, 0.f, 0.f};

    // depth-4 rolling prefetch ring; all indices static after full unroll
    float4 buf[4];
#pragma unroll
    for (int j = 0; j < 4; ++j) buf[j] = p[j * 64 + lane];

#pragma unroll
    for (int j = 0; j < 16; ++j) {
        const float4 cur = buf[j & 3];
        if (j + 4 < 16) buf[j & 3] = p[(j + 4) * 64 + lane];

        // exp-space immediately (monotone -> same top-k selection)
        const float x0 = __builtin_amdgcn_exp2f(cur.x * LOG2E);
        const float x1 = __builtin_amdgcn_exp2f(cur.y * LOG2E);
        const float x2 = __builtin_amdgcn_exp2f(cur.z * LOG2E);
        const float x3 = __builtin_amdgcn_exp2f(cur.w * LOG2E);

        const float den = grp_sum((x0 + x1) + (x2 + x3));
        const float inv = __builtin_amdgcn_rcpf(den);

        // lane-local sorted queue (desc) of its 4 exp-values
        float q0 = x0, q1 = x1, q2 = x2, q3 = x3;
        ce(q0, q1); ce(q2, q3); ce(q0, q2); ce(q1, q3); ce(q1, q2);

        // 8 pop rounds across the 16-lane group -> threshold = 8th largest of 64
        float thr = 0.f;
#pragma unroll
        for (int k = 0; k < NK; ++k) {
            const float m = grp_max(q0);
            thr = m;
            if (k < NK - 1) {
                const bool hit = (q0 == m);
                q0 = hit ? q1 : q0;
                q1 = hit ? q2 : q1;
                q2 = hit ? q3 : q2;
                q3 = hit ? -1.0f : q3;   // x >= 0 always, -1 is a safe sentinel
            }
        }

        // top-k membership counts (lane-local experts), in exp-space
        cacc[0] += (x0 >= thr) ? 1.f : 0.f;
        cacc[1] += (x1 >= thr) ? 1.f : 0.f;
        cacc[2] += (x2 >= thr) ? 1.f : 0.f;
        cacc[3] += (x3 >= thr) ? 1.f : 0.f;

        // softmax weight accumulation
        wacc[0] = fmaf(x0, inv, wacc[0]);
        wacc[1] = fmaf(x1, inv, wacc[1]);
        wacc[2] = fmaf(x2, inv, wacc[2]);
        wacc[3] = fmaf(x3, inv, wacc[3]);
    }

    // combine the 4 groups of the wave (lanes with equal (lane&15) share experts)
#pragma unroll
    for (int r = 0; r < 4; ++r) {
        wacc[r] += __shfl_xor(wacc[r], 16);
        wacc[r] += __shfl_xor(wacc[r], 32);
        cacc[r] += __shfl_xor(cacc[r], 16);
        cacc[r] += __shfl_xor(cacc[r], 32);
    }

    // block-level combine in LDS, then one batch of device-scope atomics
    __shared__ float comb[2][NE][4];
    __shared__ int last_flag;
    if (lane < 16) {
#pragma unroll
        for (int r = 0; r < 4; ++r) {
            comb[0][lane * 4 + r][wv] = wacc[r];
            comb[1][lane * 4 + r][wv] = cacc[r];
        }
    }
    __syncthreads();
    if (tid < 128) {
        const int s = tid >> 6, e = tid & 63;
        const float val = comb[s][e][0] + comb[s][e][1] + comb[s][e][2] + comb[s][e][3];
        float* dst = s ? g_c : g_w;
        atomicAdd(&dst[layer * NE + e], val);
    }
    __syncthreads();   // all atomics of this block issued before the flag bump

    if (tid == 0) {
        // release: orders this block's device-scope atomicAdds before the bump;
        // the last block's acquire synchronizes-with every release.
        const unsigned int old =
            __hip_atomic_fetch_add(cnt, 1u, __ATOMIC_ACQ_REL, __HIP_MEMORY_SCOPE_AGENT);
        last_flag = (old == NBLK - 1) ? 1 : 0;
    }
    __syncthreads();

    if (last_flag) {
        // final reduce: 2048 products, coherent atomic-loads (cross-XCD safe)
        float acc = 0.f;
#pragma unroll
        for (int k = 0; k < 8; ++k) {
            const int i = tid + k * 256;
            const float w = __hip_atomic_load(&g_w[i], __ATOMIC_RELAXED,
                                              __HIP_MEMORY_SCOPE_AGENT);
            const float c = __hip_atomic_load(&g_c[i], __ATOMIC_RELAXED,
                                              __HIP_MEMORY_SCOPE_AGENT);
            acc = fmaf(w, c, acc);
        }
        __shared__ float red[256];
        red[tid] = acc;
        __syncthreads();
        for (int s = 128; s > 0; s >>= 1) {
            if (tid < s) red[tid] += red[tid + s];
            __syncthreads();
        }
        if (tid == 0) {
            // loss = 0.01 * sum_l[ (E/(T*K)) * sum_e counts * (wsum/T) ]
            const float factor = (float)(0.01 * ((double)NE / ((double)NT * NK)) / (double)NT);
            out[0] = red[0] * factor;
        }
    }
}

extern "C" void kernel_launch(void* const* d_in, const int* in_sizes, int n_in,
                              void* d_out, int out_size, void* d_ws, size_t ws_size,
                              hipStream_t stream) {
    const float* logits = (const float*)d_in[0];
    float* g_w = (float*)d_ws;                    // [NL*NE] = 8 KB
    float* g_c = g_w + NL * NE;                   // [NL*NE] = 8 KB
    unsigned int* cnt = (unsigned int*)(g_c + NL * NE);

    // zero accumulators + completion counter (deterministic per launch, graph-safe)
    (void)hipMemsetAsync(d_ws, 0, 2 * NL * NE * sizeof(float) + sizeof(unsigned int), stream);
    bl_fused<<<dim3(NBLK), dim3(256), 0, stream>>>(logits, g_w, g_c, cnt, (float*)d_out);
}

// Round 11
// 56.181 us; speedup vs baseline: 3.2569x; 1.6405x over previous
//
#include <hip/hip_runtime.h>
#include <float.h>

#define NL 32
#define NT 16384
#define NE 64
#define NK 8
#define BPL 64               // bl_main blocks per layer (2048 blocks total)
#define LOG2E 1.4426950408889634f

// DPP control codes
#define DPP_QUAD_XOR1 0xB1   // quad_perm [1,0,3,2]
#define DPP_QUAD_XOR2 0x4E   // quad_perm [2,3,0,1]
#define DPP_ROW_ROR4  0x124  // row_ror:4
#define DPP_ROW_ROR8  0x128  // row_ror:8

template <int CTRL>
__device__ __forceinline__ float dppmv(float v) {
    return __int_as_float(
        __builtin_amdgcn_update_dpp(0, __float_as_int(v), CTRL, 0xF, 0xF, true));
}

// reduce across a 16-lane group (DPP row = 16 lanes on CDNA)
__device__ __forceinline__ float grp_max(float v) {
    v = fmaxf(v, dppmv<DPP_QUAD_XOR1>(v));
    v = fmaxf(v, dppmv<DPP_QUAD_XOR2>(v));
    v = fmaxf(v, dppmv<DPP_ROW_ROR4>(v));
    v = fmaxf(v, dppmv<DPP_ROW_ROR8>(v));
    return v;
}
__device__ __forceinline__ float grp_sum(float v) {
    v = v + dppmv<DPP_QUAD_XOR1>(v);
    v = v + dppmv<DPP_QUAD_XOR2>(v);
    v = v + dppmv<DPP_ROW_ROR4>(v);
    v = v + dppmv<DPP_ROW_ROR8>(v);
    return v;
}

// descending compare-exchange
__device__ __forceinline__ void ce(float& a, float& b) {
    float hi = fmaxf(a, b);
    float lo = fminf(a, b);
    a = hi; b = lo;
}

__global__ __launch_bounds__(256, 6) void bl_main(const float* __restrict__ logits,
                                                  float* __restrict__ partials) {
    const int tid  = threadIdx.x;
    const int lane = tid & 63;
    const int wv   = tid >> 6;
    const long slab = ((long)blockIdx.x * 4 + wv) * 64;  // first token of this wave

    // chunk j: 1KB coalesced; lane i holds experts (i&15)*4..+3 of token slab+4j+(i>>4)
    const float4* p = (const float4*)(logits + slab * NE);

    float wacc[4] = {0.f, 0.f, 0.f, 0.f};
    float cacc[4] = {0.f, 0.f, 0.f, 0.f};

    // depth-4 rolling prefetch ring; all indices static after full unroll
    float4 buf[4];
#pragma unroll
    for (int j = 0; j < 4; ++j) buf[j] = p[j * 64 + lane];

#pragma unroll
    for (int j = 0; j < 16; ++j) {
        const float4 cur = buf[j & 3];
        if (j + 4 < 16) buf[j & 3] = p[(j + 4) * 64 + lane];

        // exp-space immediately (monotone -> same top-k selection)
        const float x0 = __builtin_amdgcn_exp2f(cur.x * LOG2E);
        const float x1 = __builtin_amdgcn_exp2f(cur.y * LOG2E);
        const float x2 = __builtin_amdgcn_exp2f(cur.z * LOG2E);
        const float x3 = __builtin_amdgcn_exp2f(cur.w * LOG2E);

        const float den = grp_sum((x0 + x1) + (x2 + x3));
        const float inv = __builtin_amdgcn_rcpf(den);

        // lane-local sorted queue (desc) of its 4 exp-values
        float q0 = x0, q1 = x1, q2 = x2, q3 = x3;
        ce(q0, q1); ce(q2, q3); ce(q0, q2); ce(q1, q3); ce(q1, q2);

        // 8 pop rounds across the 16-lane group -> threshold = 8th largest of 64
        float thr = 0.f;
#pragma unroll
        for (int k = 0; k < NK; ++k) {
            const float m = grp_max(q0);
            thr = m;
            if (k < NK - 1) {
                const bool hit = (q0 == m);
                q0 = hit ? q1 : q0;
                q1 = hit ? q2 : q1;
                q2 = hit ? q3 : q2;
                q3 = hit ? -1.0f : q3;   // x >= 0 always, -1 is a safe sentinel
            }
        }

        // top-k membership counts (lane-local experts), in exp-space
        cacc[0] += (x0 >= thr) ? 1.f : 0.f;
        cacc[1] += (x1 >= thr) ? 1.f : 0.f;
        cacc[2] += (x2 >= thr) ? 1.f : 0.f;
        cacc[3] += (x3 >= thr) ? 1.f : 0.f;

        // softmax weight accumulation
        wacc[0] = fmaf(x0, inv, wacc[0]);
        wacc[1] = fmaf(x1, inv, wacc[1]);
        wacc[2] = fmaf(x2, inv, wacc[2]);
        wacc[3] = fmaf(x3, inv, wacc[3]);
    }

    // combine the 4 groups of the wave (lanes with equal (lane&15) share experts)
#pragma unroll
    for (int r = 0; r < 4; ++r) {
        wacc[r] += __shfl_xor(wacc[r], 16);
        wacc[r] += __shfl_xor(wacc[r], 32);
        cacc[r] += __shfl_xor(cacc[r], 16);
        cacc[r] += __shfl_xor(cacc[r], 32);
    }

    // block-level combine in LDS, then 128 plain coalesced stores (no atomics,
    // no memset: every partials slot is rewritten on every launch)
    __shared__ float comb[2][NE][4];
    if (lane < 16) {
#pragma unroll
        for (int r = 0; r < 4; ++r) {
            comb[0][lane * 4 + r][wv] = wacc[r];
            comb[1][lane * 4 + r][wv] = cacc[r];
        }
    }
    __syncthreads();
    if (tid < 128) {
        const int s = tid >> 6, e = tid & 63;
        const float val = comb[s][e][0] + comb[s][e][1] + comb[s][e][2] + comb[s][e][3];
        partials[(long)blockIdx.x * 128 + s * 64 + e] = val;
    }
}

__global__ __launch_bounds__(1024) void bl_final(const float* __restrict__ partials,
                                                 float* __restrict__ out) {
    const int tid  = threadIdx.x;
    const int e    = tid & 63;
    const int lsub = tid >> 6;   // 0..15
    float acc = 0.f;
#pragma unroll
    for (int half = 0; half < 2; ++half) {
        const int l = lsub + 16 * half;
        float wsum = 0.f, csum = 0.f;
        for (int b = 0; b < BPL; ++b) {
            const float* base = partials + ((long)(l * BPL + b) * 128);
            wsum += base[e];        // threads e=0..63 -> coalesced line
            csum += base[64 + e];
        }
        acc += wsum * csum;
    }
    __shared__ float red[1024];
    red[tid] = acc;
    __syncthreads();
    for (int s = 512; s > 0; s >>= 1) {
        if (tid < s) red[tid] += red[tid + s];
        __syncthreads();
    }
    if (tid == 0) {
        // loss = 0.01 * sum_l[ (E/(T*K)) * sum_e counts * (wsum/T) ]
        const float factor = (float)(0.01 * ((double)NE / ((double)NT * NK)) / (double)NT);
        out[0] = red[0] * factor;
    }
}

extern "C" void kernel_launch(void* const* d_in, const int* in_sizes, int n_in,
                              void* d_out, int out_size, void* d_ws, size_t ws_size,
                              hipStream_t stream) {
    const float* logits = (const float*)d_in[0];
    float* partials = (float*)d_ws;   // [2048 blocks][128] = 1 MB, fully rewritten
                                      // by bl_main before bl_final reads it

    bl_main<<<dim3(NL * BPL), dim3(256), 0, stream>>>(logits, partials);
    bl_final<<<dim3(1), dim3(1024), 0, stream>>>(partials, (float*)d_out);
}

// Round 12
// 51.439 us; speedup vs baseline: 3.5571x; 1.0922x over previous
//
#include <hip/hip_runtime.h>
#include <float.h>

#define NL 32
#define NT 16384
#define NE 64
#define NK 8
#define BPL 64               // bl_main blocks per layer (2048 blocks total)
#define LOG2E 1.4426950408889634f

// DPP control codes
#define DPP_QUAD_XOR1 0xB1   // quad_perm [1,0,3,2]
#define DPP_QUAD_XOR2 0x4E   // quad_perm [2,3,0,1]
#define DPP_ROW_ROR4  0x124  // row_ror:4
#define DPP_ROW_ROR8  0x128  // row_ror:8

template <int CTRL>
__device__ __forceinline__ float dppmv(float v) {
    return __int_as_float(
        __builtin_amdgcn_update_dpp(0, __float_as_int(v), CTRL, 0xF, 0xF, true));
}

// reduce across a 16-lane group (DPP row = 16 lanes on CDNA)
__device__ __forceinline__ float grp_max(float v) {
    v = fmaxf(v, dppmv<DPP_QUAD_XOR1>(v));
    v = fmaxf(v, dppmv<DPP_QUAD_XOR2>(v));
    v = fmaxf(v, dppmv<DPP_ROW_ROR4>(v));
    v = fmaxf(v, dppmv<DPP_ROW_ROR8>(v));
    return v;
}
__device__ __forceinline__ float grp_sum(float v) {
    v = v + dppmv<DPP_QUAD_XOR1>(v);
    v = v + dppmv<DPP_QUAD_XOR2>(v);
    v = v + dppmv<DPP_ROW_ROR4>(v);
    v = v + dppmv<DPP_ROW_ROR8>(v);
    return v;
}

// descending compare-exchange
__device__ __forceinline__ void ce(float& a, float& b) {
    float hi = fmaxf(a, b);
    float lo = fminf(a, b);
    a = hi; b = lo;
}

__global__ __launch_bounds__(256, 6) void bl_main(const float* __restrict__ logits,
                                                  float* __restrict__ partials) {
    const int tid  = threadIdx.x;
    const int lane = tid & 63;
    const int wv   = tid >> 6;
    const long slab = ((long)blockIdx.x * 4 + wv) * 64;  // first token of this wave

    // chunk j: 1KB coalesced; lane i holds experts (i&15)*4..+3 of token slab+4j+(i>>4)
    const float4* p = (const float4*)(logits + slab * NE);

    float wacc[4] = {0.f, 0.f, 0.f, 0.f};
    float cacc[4] = {0.f, 0.f, 0.f, 0.f};

    // depth-4 rolling prefetch ring; all indices static after full unroll
    float4 buf[4];
#pragma unroll
    for (int j = 0; j < 4; ++j) buf[j] = p[j * 64 + lane];

#pragma unroll
    for (int j = 0; j < 16; ++j) {
        const float4 cur = buf[j & 3];
        if (j + 4 < 16) buf[j & 3] = p[(j + 4) * 64 + lane];

        // exp-space immediately (monotone -> same top-k selection)
        const float x0 = __builtin_amdgcn_exp2f(cur.x * LOG2E);
        const float x1 = __builtin_amdgcn_exp2f(cur.y * LOG2E);
        const float x2 = __builtin_amdgcn_exp2f(cur.z * LOG2E);
        const float x3 = __builtin_amdgcn_exp2f(cur.w * LOG2E);

        const float den = grp_sum((x0 + x1) + (x2 + x3));
        const float inv = __builtin_amdgcn_rcpf(den);

        // lane-local sorted queue (desc) of its 4 exp-values
        float q0 = x0, q1 = x1, q2 = x2, q3 = x3;
        ce(q0, q1); ce(q2, q3); ce(q0, q2); ce(q1, q3); ce(q1, q2);

        // 8 pop rounds across the 16-lane group -> threshold = 8th largest of 64
        float thr = 0.f;
#pragma unroll
        for (int k = 0; k < NK; ++k) {
            const float m = grp_max(q0);
            thr = m;
            if (k < NK - 1) {
                const bool hit = (q0 == m);
                q0 = hit ? q1 : q0;
                q1 = hit ? q2 : q1;
                q2 = hit ? q3 : q2;
                q3 = hit ? -1.0f : q3;   // x >= 0 always, -1 is a safe sentinel
            }
        }

        // top-k membership counts (lane-local experts), in exp-space
        cacc[0] += (x0 >= thr) ? 1.f : 0.f;
        cacc[1] += (x1 >= thr) ? 1.f : 0.f;
        cacc[2] += (x2 >= thr) ? 1.f : 0.f;
        cacc[3] += (x3 >= thr) ? 1.f : 0.f;

        // softmax weight accumulation
        wacc[0] = fmaf(x0, inv, wacc[0]);
        wacc[1] = fmaf(x1, inv, wacc[1]);
        wacc[2] = fmaf(x2, inv, wacc[2]);
        wacc[3] = fmaf(x3, inv, wacc[3]);
    }

    // combine the 4 groups of the wave (lanes with equal (lane&15) share experts)
#pragma unroll
    for (int r = 0; r < 4; ++r) {
        wacc[r] += __shfl_xor(wacc[r], 16);
        wacc[r] += __shfl_xor(wacc[r], 32);
        cacc[r] += __shfl_xor(cacc[r], 16);
        cacc[r] += __shfl_xor(cacc[r], 32);
    }

    // block-level combine in LDS, then 128 plain coalesced stores (no atomics,
    // no memset: every partials slot is rewritten on every launch)
    __shared__ float comb[2][NE][4];
    if (lane < 16) {
#pragma unroll
        for (int r = 0; r < 4; ++r) {
            comb[0][lane * 4 + r][wv] = wacc[r];
            comb[1][lane * 4 + r][wv] = cacc[r];
        }
    }
    __syncthreads();
    if (tid < 128) {
        const int s = tid >> 6, e = tid & 63;
        const float val = comb[s][e][0] + comb[s][e][1] + comb[s][e][2] + comb[s][e][3];
        partials[(long)blockIdx.x * 128 + s * 64 + e] = val;
    }
}

// one block per layer: reduce 64 blocks' [128] partials -> layerdot[l]
__global__ __launch_bounds__(256) void bl_red(const float* __restrict__ partials,
                                              float* __restrict__ layerdot) {
    const int l   = blockIdx.x;
    const int tid = threadIdx.x;
    const int e   = tid & 63;
    const int sub = tid >> 6;    // 0..3: 4 sub-groups each handle 16 blocks
    float wsum = 0.f, csum = 0.f;
    for (int b = sub; b < BPL; b += 4) {
        const float* base = partials + ((long)(l * BPL + b) * 128);
        wsum += base[e];
        csum += base[64 + e];
    }
    // combine the 4 sub-groups' partial sums via LDS
    __shared__ float ws[4][NE], cs[4][NE];
    ws[sub][e] = wsum;
    cs[sub][e] = csum;
    __syncthreads();
    if (tid < NE) {
        const float w = ws[0][e] + ws[1][e] + ws[2][e] + ws[3][e];
        const float c = cs[0][e] + cs[1][e] + cs[2][e] + cs[3][e];
        float d = w * c;
        // wave-reduce 64 lanes -> lane 0
        for (int s = 1; s < 64; s <<= 1) d += __shfl_xor(d, s);
        if (e == 0) layerdot[l] = d;
    }
}

__global__ void bl_fin(const float* __restrict__ layerdot, float* __restrict__ out) {
    const int tid = threadIdx.x;   // 64 threads
    float d = (tid < NL) ? layerdot[tid] : 0.f;
    for (int s = 1; s < 64; s <<= 1) d += __shfl_xor(d, s);
    if (tid == 0) {
        // loss = 0.01 * sum_l[ (E/(T*K)) * sum_e counts * (wsum/T) ]
        const float factor = (float)(0.01 * ((double)NE / ((double)NT * NK)) / (double)NT);
        out[0] = d * factor;
    }
}

extern "C" void kernel_launch(void* const* d_in, const int* in_sizes, int n_in,
                              void* d_out, int out_size, void* d_ws, size_t ws_size,
                              hipStream_t stream) {
    const float* logits = (const float*)d_in[0];
    float* partials = (float*)d_ws;            // [2048][128] = 1 MB, fully rewritten
    float* layerdot = partials + 2048 * 128;   // [32], fully rewritten

    bl_main<<<dim3(NL * BPL), dim3(256), 0, stream>>>(logits, partials);
    bl_red<<<dim3(NL), dim3(256), 0, stream>>>(partials, layerdot);
    bl_fin<<<dim3(1), dim3(64), 0, stream>>>(layerdot, (float*)d_out);
}